// Round 6
// baseline (5530.279 us; speedup 1.0000x reference)
//
#include <hip/hip_runtime.h>

#define T_STEPS 2048
#define NBATCH  256
#define EDIM    128
#define HDIM    256
#define NVOCAB  50001
#define NGROUPS 16
#define NSLICES 32
#define NBLOCKS (NGROUPS*NSLICES)

typedef _Float16 half8 __attribute__((ext_vector_type(8)));
typedef float    floatx4 __attribute__((ext_vector_type(4)));
typedef int      intx8  __attribute__((ext_vector_type(8)));
typedef unsigned int uint32;

#define LOG2E      1.4426950408889634f
#define TWO_LOG2E  2.8853900817779268f

// pre-activations arrive pre-scaled by LOG2E (sigmoid) / 2*LOG2E (tanh)
__device__ __forceinline__ float sigE(float x){   // x = LOG2E * z ; returns sigmoid(z)
    return __builtin_amdgcn_rcpf(1.0f + __builtin_amdgcn_exp2f(-x));
}
__device__ __forceinline__ float tanhE(float x){  // x = 2*LOG2E * z ; returns tanh(z)
    return 2.0f * __builtin_amdgcn_rcpf(1.0f + __builtin_amdgcn_exp2f(-x)) - 1.0f;
}
__device__ __forceinline__ float sigm(float x){ return 1.0f/(1.0f + __expf(-x)); }
__device__ __forceinline__ float tanh_fast(float x){ return 2.0f/(1.0f + __expf(-2.0f*x)) - 1.0f; }

// ============================================================================
// PATH B (ws >= 102.4 MB): xg vocab table [v][j][gate] (pre-scaled) + 64-CU
// persistent LSTM (4 batch rows per CU), MX K=128 fp8 recurrent MFMA,
// shuffle-free q-extraction gate math (1 cell per lane).
// ============================================================================
#define TABLE_BYTES ((size_t)NVOCAB * 1024 * 2)   // 102,402,048
#define W8_BYTES    (4*HDIM*HDIM)                 // 262,144 packed fp8 W_hh
#define WS_B2       (TABLE_BYTES + W8_BYTES)

// xg_table: xgp[v][j][gate] (f16, gates 0..3 contiguous = 8B) =
//   scale(gate) * ( sum_e W_ih[gate*256+j, e]*emb[v,e] + b_ih[..] + b_hh[..] )
// g-gate (gate==2) scale 2*LOG2E, else LOG2E.
__global__ __launch_bounds__(64, 1) void xg_table(
    const float* __restrict__ emb,
    const float* __restrict__ Wih,
    const float* __restrict__ bih,
    const float* __restrict__ bhh,
    _Float16*    __restrict__ xgp)
{
    const int L  = threadIdx.x;
    const int l15 = L & 15;
    const int q   = L >> 4;
    const int w   = blockIdx.x & 7;
    const int v0  = (blockIdx.x >> 3) * 64;

    // B-fragment cols: col(n,w,l15) = (n>>1)*256 + w*32 + (n&1)*16 + l15
    half8 bfr[8][4];
    float bias[8];
    #pragma unroll
    for (int n = 0; n < 8; ++n) {
        const int col = (n >> 1)*256 + w*32 + (n & 1)*16 + l15;
        bias[n] = bih[col] + bhh[col];
        #pragma unroll
        for (int kt = 0; kt < 4; ++kt) {
            const float* p = Wih + col*EDIM + kt*32 + q*8;
            const float4 f0 = *(const float4*)p;
            const float4 f1 = *(const float4*)(p + 4);
            half8 h;
            h[0]=(_Float16)f0.x; h[1]=(_Float16)f0.y; h[2]=(_Float16)f0.z; h[3]=(_Float16)f0.w;
            h[4]=(_Float16)f1.x; h[5]=(_Float16)f1.y; h[6]=(_Float16)f1.z; h[7]=(_Float16)f1.w;
            bfr[n][kt] = h;
        }
    }

    floatx4 acc[4][8];
    #pragma unroll
    for (int mt = 0; mt < 4; ++mt)
        #pragma unroll
        for (int n = 0; n < 8; ++n) acc[mt][n] = (floatx4){0.f,0.f,0.f,0.f};

    #pragma unroll
    for (int mt = 0; mt < 4; ++mt) {
        int v = v0 + mt*16 + l15;
        if (v > NVOCAB-1) v = NVOCAB-1;
        #pragma unroll
        for (int kt = 0; kt < 4; ++kt) {
            const float* p = emb + (size_t)v*EDIM + kt*32 + q*8;
            const float4 f0 = *(const float4*)p;
            const float4 f1 = *(const float4*)(p + 4);
            half8 a;
            a[0]=(_Float16)f0.x; a[1]=(_Float16)f0.y; a[2]=(_Float16)f0.z; a[3]=(_Float16)f0.w;
            a[4]=(_Float16)f1.x; a[5]=(_Float16)f1.y; a[6]=(_Float16)f1.z; a[7]=(_Float16)f1.w;
            #pragma unroll
            for (int n = 0; n < 8; ++n)
                acc[mt][n] = __builtin_amdgcn_mfma_f32_16x16x32_f16(a, bfr[n][kt], acc[mt][n], 0,0,0);
        }
    }

    // store: n even -> j0 = w*32+l15 ; n odd -> j1 = j0+16 ; gate = n>>1
    #pragma unroll
    for (int mt = 0; mt < 4; ++mt) {
        #pragma unroll
        for (int r = 0; r < 4; ++r) {
            const int v = v0 + mt*16 + q*4 + r;
            if (v <= NVOCAB-1) {
                union { uint2 u; _Float16 h[4]; } e0, e1;
                #pragma unroll
                for (int g = 0; g < 4; ++g) {
                    const float sc = (g == 2) ? TWO_LOG2E : LOG2E;
                    e0.h[g] = (_Float16)((acc[mt][2*g  ][r] + bias[2*g  ]) * sc);
                    e1.h[g] = (_Float16)((acc[mt][2*g+1][r] + bias[2*g+1]) * sc);
                }
                const int j0 = w*32 + l15;
                *(uint2*)(xgp + (size_t)v*1024 + j0*4)        = e0.u;
                *(uint2*)(xgp + (size_t)v*1024 + (j0+16)*4)   = e1.u;
            }
        }
    }
}

// w8_cvt: pack scaled W_hh to fp8-e4m3, row-major [col][k] (bytes).
// byte offset = col*256 + k ; scale LOG2E (2*LOG2E for g-gate cols 512..767).
__global__ __launch_bounds__(256) void w8_cvt(const float* __restrict__ Whh,
                                              int* __restrict__ w8)
{
    const int tid = blockIdx.x*256 + threadIdx.x;   // 0..32767
    const int col = tid >> 5;
    const int k8  = (tid & 31) * 8;
    const float sc = ((col >> 8) == 2) ? TWO_LOG2E : LOG2E;
    const float* p = Whh + col*HDIM + k8;
    const float4 f0 = *(const float4*)p;
    const float4 f1 = *(const float4*)(p + 4);
    int lo = __builtin_amdgcn_cvt_pk_fp8_f32(f0.x*sc, f0.y*sc, 0, false);
    lo     = __builtin_amdgcn_cvt_pk_fp8_f32(f0.z*sc, f0.w*sc, lo, true);
    int hi = __builtin_amdgcn_cvt_pk_fp8_f32(f1.x*sc, f1.y*sc, 0, false);
    hi     = __builtin_amdgcn_cvt_pk_fp8_f32(f1.z*sc, f1.w*sc, hi, true);
    ((int2*)w8)[tid] = make_int2(lo, hi);
}

// Persistent LSTM: 64 blocks x 1024 threads (16 waves), 4 batch rows per block.
// A rows aliased (m&3) => D row q*4+r == cell-row r for every q, so all quads
// hold identical accumulators; lane (l15,q) extracts acc[g][q] (3 cndmask/gate,
// no shuffles) and owns exactly one cell (row=q, j=wv*16+l15).
// waves_per_eu(4,4) pins the VGPR budget at 128 so wf stays register-resident
// (round-5 regression: compiler targeted 8 waves/EU, VGPR=64, respilled wf).
#define NBLK3     64
#define HS3       272                      // fp8 h row stride (bytes)
#define H8B3      (4*HS3)                  // 1088 per parity
#define SM3_H8    0
#define SM3_HF16  (2*H8B3)                 // 2176
#define SM3_RED   (SM3_HF16 + 4*256*2)     // 4224
#define SM3_TOT   (SM3_RED + 64*4)         // 4480

__global__ __launch_bounds__(1024)
__attribute__((amdgpu_waves_per_eu(4, 4)))
void lstm_table(
    const int*   __restrict__ tok,
    const float* __restrict__ Whh,
    const float* __restrict__ Wout,
    const float* __restrict__ bout,
    const _Float16* __restrict__ xgp,
    const char*  __restrict__ w8,
    int use_w8,
    float*       __restrict__ out)
{
    __shared__ char smem[SM3_TOT];
    const int tid = threadIdx.x;
    const int wv  = tid >> 6;      // 0..15
    const int L   = tid & 63;
    const int l15 = L & 15;
    const int q   = L >> 4;        // 0..3 = this lane's batch row
    const int g4  = blockIdx.x * 4;
    const int jme = wv*16 + l15;

    // ---- W_hh fp8 MX fragments: wf[n][kt], 32 B/lane = k in [kt*128+q*32,+32)
    // for col = n*256 + jme (gate n of column j = jme).
    intx8 wf[4][2];
    if (use_w8) {
        #pragma unroll
        for (int n = 0; n < 4; ++n) {
            const char* pc = w8 + (n*256 + jme)*256 + q*32;
            #pragma unroll
            for (int kt = 0; kt < 2; ++kt) {
                union { int4 v[2]; intx8 a; } u;
                u.v[0] = *(const int4*)(pc + kt*128);
                u.v[1] = *(const int4*)(pc + kt*128 + 16);
                wf[n][kt] = u.a;
            }
        }
    } else {
        #pragma unroll
        for (int n = 0; n < 4; ++n) {
            const int col = n*256 + jme;
            const float sc = (n == 2) ? TWO_LOG2E : LOG2E;
            #pragma unroll
            for (int kt = 0; kt < 2; ++kt) {
                const float* p = Whh + col*HDIM + kt*128 + q*32;
                intx8 v;
                #pragma unroll
                for (int d = 0; d < 8; ++d) {
                    const float4 f = *(const float4*)(p + d*4);
                    int pk = __builtin_amdgcn_cvt_pk_fp8_f32(f.x*sc, f.y*sc, 0, false);
                    pk     = __builtin_amdgcn_cvt_pk_fp8_f32(f.z*sc, f.w*sc, pk, true);
                    v[d] = pk;
                }
                wf[n][kt] = v;
            }
        }
    }

    // ---- pipeline init ----
    const int myrow = g4 + q;
    uint2 xg_cur, xg_nxt;
    int tk_c, tk_n;
    xg_cur = *(const uint2*)(xgp + (size_t)tok[myrow]*1024 + jme*4);
    tk_c   = tok[NBATCH + myrow];

    float c = 0.f;

    #pragma unroll 1
    for (int t = 0; t < T_STEPS; ++t) {
        if (t + 2 < T_STEPS) tk_n = tok[(t+2)*NBATCH + myrow];
        if (t + 1 < T_STEPS)
            xg_nxt = *(const uint2*)(xgp + (size_t)tk_c*1024 + jme*4);

        floatx4 acc[4];
        #pragma unroll
        for (int n = 0; n < 4; ++n) acc[n] = (floatx4){0.f,0.f,0.f,0.f};

        // recurrent GEMM: A = fp8 h from LDS, row (l15&3), bytes kt*128+q*32
        if (t > 0) {
            const char* hb = smem + SM3_H8 + ((t-1) & 1)*H8B3 + (l15 & 3)*HS3 + q*32;
            union { int4 v[2]; intx8 a; } af0, af1;
            af0.v[0] = *(const int4*)(hb);
            af0.v[1] = *(const int4*)(hb + 16);
            af1.v[0] = *(const int4*)(hb + 128);
            af1.v[1] = *(const int4*)(hb + 128 + 16);
            #pragma unroll
            for (int n = 0; n < 4; ++n)
                acc[n] = __builtin_amdgcn_mfma_scale_f32_16x16x128_f8f6f4(
                             af0.a, wf[n][0], acc[n], 0, 0, 0, 127, 0, 127);
            #pragma unroll
            for (int n = 0; n < 4; ++n)
                acc[n] = __builtin_amdgcn_mfma_scale_f32_16x16x128_f8f6f4(
                             af1.a, wf[n][1], acc[n], 0, 0, 0, 127, 0, 127);
        }

        // extract this lane's row (q) from the replicated accumulators
        const bool b0 = (q & 1);
        const bool b1 = (q >= 2);
        float P[4];
        #pragma unroll
        for (int g = 0; g < 4; ++g) {
            const float t01 = b0 ? acc[g][1] : acc[g][0];
            const float t23 = b0 ? acc[g][3] : acc[g][2];
            P[g] = b1 ? t23 : t01;
        }
        // add xg (pre-scaled)
        {
            union { uint2 u; _Float16 h[4]; } xv; xv.u = xg_cur;
            P[0] += (float)xv.h[0];
            P[1] += (float)xv.h[1];
            P[2] += (float)xv.h[2];
            P[3] += (float)xv.h[3];
        }

        const float iv = sigE(P[0]);
        const float fv = sigE(P[1]);
        const float gv = tanhE(P[2]);
        const float ov = sigE(P[3]);
        const float cn = fv * c + iv * gv;
        c = cn;
        const float hv = ov * tanhE(cn * TWO_LOG2E);

        if (t == T_STEPS-1) {
            *(_Float16*)(smem + SM3_HF16 + (q*256 + jme)*2) = (_Float16)hv;
        } else {
            const int pk = __builtin_amdgcn_cvt_pk_fp8_f32(hv, hv, 0, false);
            *(char*)(smem + SM3_H8 + (t & 1)*H8B3 + q*HS3 + jme) = (char)pk;
        }
        __syncthreads();

        xg_cur = xg_nxt;
        tk_c   = tk_n;
    }

    // ---- output: y = sigmoid(h_T . W_out + b) for 4 rows ----
    float* red = (float*)(smem + SM3_RED);
    if (tid < 64) {
        const int b = tid >> 4, seg = tid & 15;
        const _Float16* hr = (const _Float16*)(smem + SM3_HF16) + b*256 + seg*16;
        const float* wo = Wout + seg*16;
        float s = 0.f;
        #pragma unroll
        for (int jj = 0; jj < 16; ++jj) s += (float)hr[jj] * wo[jj];
        red[tid] = s;
    }
    __syncthreads();
    if (tid < 4) {
        float s = 0.f;
        #pragma unroll
        for (int k = 0; k < 16; ++k) s += red[tid*16 + k];
        out[g4 + tid] = sigm(s + bout[0]);
    }
}

// ============================================================================
// PATH A (fallback, ws < 102.4 MB): Round-1 kernel (proven, ~8.4 ms)
// ============================================================================
#define FLAGS_OFF   0
#define HBUF_OFF    4096
#define EMB16_OFF   (4096 + 262144)
#define EMB16_BYTES (NVOCAB*EDIM*2)
#define WS_NEED_BIG (EMB16_OFF + EMB16_BYTES)

__global__ void emb_cvt_kernel(const float* __restrict__ src, _Float16* __restrict__ dst, int n4){
    int stride = gridDim.x * blockDim.x;
    for (int i = blockIdx.x*blockDim.x + threadIdx.x; i < n4; i += stride) {
        const float4 v = ((const float4*)src)[i];
        union { _Float16 h[4]; uint2 u; } p;
        p.h[0] = (_Float16)v.x; p.h[1] = (_Float16)v.y;
        p.h[2] = (_Float16)v.z; p.h[3] = (_Float16)v.w;
        ((uint2*)dst)[i] = p.u;
    }
}

__global__ __launch_bounds__(64, 2) void lstm_persist(
    const int*   __restrict__ tok,
    const float* __restrict__ emb32,
    const float* __restrict__ Wih,
    const float* __restrict__ Whh,
    const float* __restrict__ bih,
    const float* __restrict__ bhh,
    const float* __restrict__ Wout,
    const float* __restrict__ bout,
    float*       __restrict__ out,
    char*        __restrict__ ws,
    const _Float16* __restrict__ emb16,
    int use16)
{
    const int L      = threadIdx.x;
    const int lane15 = L & 15;
    const int quad   = L >> 4;
    const int bid    = blockIdx.x;
    const int grp    = (bid & 7)*2 + (bid >> 8);
    const int slc    = (bid >> 3) & 31;

    int*      flags = (int*)(ws + FLAGS_OFF);
    _Float16* hbuf  = (_Float16*)(ws + HBUF_OFF);

    half8 bfr[2][12];
    float bias[2];
    #pragma unroll
    for (int tile = 0; tile < 2; ++tile) {
        const int nloc = tile*16 + lane15;
        const int gate = nloc >> 3;
        const int jj   = nloc & 7;
        const int ng   = gate*HDIM + slc*8 + jj;
        bias[tile] = bih[ng] + bhh[ng];
        #pragma unroll
        for (int kt = 0; kt < 12; ++kt) {
            const int k0 = kt*32 + quad*8;
            const float* p = (kt < 4) ? (Wih + ng*EDIM + k0)
                                      : (Whh + ng*HDIM + (k0 - EDIM));
            half8 h;
            #pragma unroll
            for (int i = 0; i < 8; ++i) h[i] = (_Float16)p[i];
            bfr[tile][kt] = h;
        }
    }

    const int btok = grp*16 + lane15;
    auto ldx = [&](int tk, int kt) -> half8 {
        const int k0 = kt*32 + quad*8;
        if (use16) {
            return *(const half8*)(emb16 + (long)tk*EDIM + k0);
        } else {
            const float* p = emb32 + (long)tk*EDIM + k0;
            half8 h;
            #pragma unroll
            for (int i = 0; i < 8; ++i) h[i] = (_Float16)p[i];
            return h;
        }
    };

    int tok_next = tok[NBATCH + btok];
    half8 xcur[4], xnext[4];
    {
        int tok0 = tok[btok];
        #pragma unroll
        for (int kt = 0; kt < 4; ++kt) xcur[kt] = ldx(tok0, kt);
    }

    float c[4] = {0.f, 0.f, 0.f, 0.f};
    const bool act = (lane15 < 8);
    const bool stl = act && !(lane15 & 1);
    const int  jj8 = lane15 & 7;

    #pragma unroll 1
    for (int t = 0; t < T_STEPS; ++t) {
        if (t + 1 < T_STEPS) {
            #pragma unroll
            for (int kt = 0; kt < 4; ++kt) xnext[kt] = ldx(tok_next, kt);
        }
        int tok_nn = 0;
        if (t + 2 < T_STEPS) tok_nn = tok[(t+2)*NBATCH + btok];

        floatx4 acc0 = {0.f,0.f,0.f,0.f};
        floatx4 acc1 = {0.f,0.f,0.f,0.f};

        #pragma unroll
        for (int kt = 0; kt < 4; ++kt) {
            acc0 = __builtin_amdgcn_mfma_f32_16x16x32_f16(xcur[kt], bfr[0][kt], acc0, 0,0,0);
            acc1 = __builtin_amdgcn_mfma_f32_16x16x32_f16(xcur[kt], bfr[1][kt], acc1, 0,0,0);
        }

        if (t > 0) {
            const int parR = (t-1) & 1;
            int* fl = flags + parR*(NGROUPS*NSLICES) + grp*NSLICES + (L & 31);
            int cnt = 0;
            while (true) {
                int v = __hip_atomic_load(fl, __ATOMIC_RELAXED, __HIP_MEMORY_SCOPE_AGENT);
                if (__all(v >= t)) break;
                if (++cnt > (1<<15)) break;
                __builtin_amdgcn_s_sleep(1);
            }
            asm volatile("" ::: "memory");
            const _Float16* hr = hbuf + (parR*NGROUPS + grp)*(16*HDIM) + lane15*HDIM;
            #pragma unroll
            for (int kt = 4; kt < 12; ++kt) {
                const int j0 = (kt-4)*32 + quad*8;
                const uint32* hp = (const uint32*)(hr + j0);
                union { uint32 u[4]; half8 h; } hf;
                hf.u[0] = __hip_atomic_load(hp+0, __ATOMIC_RELAXED, __HIP_MEMORY_SCOPE_AGENT);
                hf.u[1] = __hip_atomic_load(hp+1, __ATOMIC_RELAXED, __HIP_MEMORY_SCOPE_AGENT);
                hf.u[2] = __hip_atomic_load(hp+2, __ATOMIC_RELAXED, __HIP_MEMORY_SCOPE_AGENT);
                hf.u[3] = __hip_atomic_load(hp+3, __ATOMIC_RELAXED, __HIP_MEMORY_SCOPE_AGENT);
                acc0 = __builtin_amdgcn_mfma_f32_16x16x32_f16(hf.h, bfr[0][kt], acc0, 0,0,0);
                acc1 = __builtin_amdgcn_mfma_f32_16x16x32_f16(hf.h, bfr[1][kt], acc1, 0,0,0);
            }
        }

        uint32 hdw[4];
        #pragma unroll
        for (int r = 0; r < 4; ++r) {
            float p0 = acc0[r] + bias[0];
            float p1 = acc1[r] + bias[1];
            float fpre = __int_as_float(__builtin_amdgcn_ds_swizzle(__float_as_int(p0), 0x201F));
            float opre = __int_as_float(__builtin_amdgcn_ds_swizzle(__float_as_int(p1), 0x201F));
            float iv = sigm(p0);
            float fv = sigm(fpre);
            float gv = tanh_fast(p1);
            float ov = sigm(opre);
            float cn = fv * c[r] + iv * gv;
            c[r] = cn;
            float hv = ov * tanh_fast(cn);
            union { _Float16 f; unsigned short u; } cvh; cvh.f = (_Float16)hv;
            uint32 hu = cvh.u;
            uint32 part = (uint32)__builtin_amdgcn_ds_swizzle((int)hu, 0x041F);
            hdw[r] = (hu & 0xFFFFu) | (part << 16);
        }
        {
            _Float16* hwb = hbuf + (((t&1)*NGROUPS) + grp)*(16*HDIM);
            if (stl) {
                #pragma unroll
                for (int r = 0; r < 4; ++r) {
                    const int m = quad*4 + r;
                    uint32* dst = (uint32*)(hwb + m*HDIM + slc*8 + jj8);
                    __hip_atomic_store(dst, hdw[r], __ATOMIC_RELAXED, __HIP_MEMORY_SCOPE_AGENT);
                }
            }
            asm volatile("s_waitcnt vmcnt(0)" ::: "memory");
            if (L == 0) {
                int* myf = flags + (t&1)*(NGROUPS*NSLICES) + grp*NSLICES + slc;
                __hip_atomic_store(myf, t+1, __ATOMIC_RELAXED, __HIP_MEMORY_SCOPE_AGENT);
            }
        }
        #pragma unroll
        for (int kt = 0; kt < 4; ++kt) xcur[kt] = xnext[kt];
        tok_next = tok_nn;
    }

    if (slc == 0) {
        const int parF = (T_STEPS-1) & 1;
        int* fl = flags + parF*(NGROUPS*NSLICES) + grp*NSLICES + (L & 31);
        int cnt = 0;
        while (true) {
            int v = __hip_atomic_load(fl, __ATOMIC_RELAXED, __HIP_MEMORY_SCOPE_AGENT);
            if (__all(v >= T_STEPS)) break;
            if (++cnt > (1<<15)) break;
            __builtin_amdgcn_s_sleep(1);
        }
        asm volatile("" ::: "memory");
        const int m  = L >> 2;
        const int pp = L & 3;
        const _Float16* hr = hbuf + (parF*NGROUPS + grp)*(16*HDIM) + m*HDIM;
        const uint32* hp = (const uint32*)hr + pp*32;
        float sum = 0.f;
        #pragma unroll
        for (int d = 0; d < 32; ++d) {
            uint32 u = __hip_atomic_load(hp + d, __ATOMIC_RELAXED, __HIP_MEMORY_SCOPE_AGENT);
            union { uint32 u; _Float16 h[2]; } cv; cv.u = u;
            const int j = pp*64 + d*2;
            sum += (float)cv.h[0] * Wout[j] + (float)cv.h[1] * Wout[j+1];
        }
        sum += __int_as_float(__builtin_amdgcn_ds_swizzle(__float_as_int(sum), 0x041F));
        sum += __int_as_float(__builtin_amdgcn_ds_swizzle(__float_as_int(sum), 0x081F));
        if (pp == 0) out[grp*16 + m] = sigm(sum + bout[0]);
    }
}

// ============================================================================
extern "C" void kernel_launch(void* const* d_in, const int* in_sizes, int n_in,
                              void* d_out, int out_size, void* d_ws, size_t ws_size,
                              hipStream_t stream) {
    const int*   tokp = (const int*)  d_in[0];
    const float* emb  = (const float*)d_in[1];
    const float* Wih  = (const float*)d_in[2];
    const float* Whh  = (const float*)d_in[3];
    const float* bih  = (const float*)d_in[4];
    const float* bhh  = (const float*)d_in[5];
    const float* Wout = (const float*)d_in[6];
    const float* bout = (const float*)d_in[7];
    float* out = (float*)d_out;
    char*  ws  = (char*)d_ws;

    if (ws_size >= TABLE_BYTES) {
        _Float16* xgp = (_Float16*)ws;
        const int use_w8 = (ws_size >= WS_B2) ? 1 : 0;
        int* w8 = (int*)(ws + TABLE_BYTES);
        const int vtiles = (NVOCAB + 63) / 64;          // 782
        xg_table<<<vtiles*8, 64, 0, stream>>>(emb, Wih, bih, bhh, xgp);
        if (use_w8) w8_cvt<<<128, 256, 0, stream>>>(Whh, w8);
        lstm_table<<<NBLK3, 1024, 0, stream>>>(tokp, Whh, Wout, bout, xgp,
                                               (const char*)w8, use_w8, out);
    } else {
        const int use16 = (ws_size >= (size_t)WS_NEED_BIG) ? 1 : 0;
        _Float16* emb16 = (_Float16*)(ws + EMB16_OFF);
        if (use16) {
            emb_cvt_kernel<<<1024, 256, 0, stream>>>(emb, emb16, NVOCAB*EDIM/4);
        }
        lstm_persist<<<NBLOCKS, 64, 0, stream>>>(tokp, emb, Wih, Whh, bih, bhh, Wout, bout,
                                                 out, ws, emb16, use16);
    }
}

// Round 7
// 2223.049 us; speedup vs baseline: 2.4877x; 2.4877x over previous
//
#include <hip/hip_runtime.h>

#define T_STEPS 2048
#define NBATCH  256
#define EDIM    128
#define HDIM    256
#define NVOCAB  50001
#define NGROUPS 16
#define NSLICES 32
#define NBLOCKS (NGROUPS*NSLICES)

typedef _Float16 half8 __attribute__((ext_vector_type(8)));
typedef float    floatx4 __attribute__((ext_vector_type(4)));
typedef int      intx8  __attribute__((ext_vector_type(8)));
typedef unsigned int uint32;

#define LOG2E      1.4426950408889634f
#define TWO_LOG2E  2.8853900817779268f

// pre-activations arrive pre-scaled by LOG2E (sigmoid) / 2*LOG2E (tanh)
__device__ __forceinline__ float sigE(float x){   // x = LOG2E * z ; returns sigmoid(z)
    return __builtin_amdgcn_rcpf(1.0f + __builtin_amdgcn_exp2f(-x));
}
__device__ __forceinline__ float tanhE(float x){  // x = 2*LOG2E * z ; returns tanh(z)
    return 2.0f * __builtin_amdgcn_rcpf(1.0f + __builtin_amdgcn_exp2f(-x)) - 1.0f;
}
__device__ __forceinline__ float sigm(float x){ return 1.0f/(1.0f + __expf(-x)); }
__device__ __forceinline__ float tanh_fast(float x){ return 2.0f/(1.0f + __expf(-2.0f*x)) - 1.0f; }

// ============================================================================
// PATH B (ws >= 102.4 MB): xg vocab table [v][jpair][8 gates] (pre-scaled) +
// 64-CU persistent LSTM (4 rows/CU, 8 waves), depth-2 unrolled xg prefetch,
// adjacent-column cell pairing, MX K=128 fp8 recurrent MFMA.
// ============================================================================
#define TABLE_BYTES ((size_t)NVOCAB * 1024 * 2)   // 102,402,048

// xg_table layout: entry(v, jp) = 8 f16 = {i,f,g,o for col j0} {i,f,g,o for j0+1}
// where jp = w*16 + l15, j0 = w*32 + 2*l15. Writer B-frag col mapping:
// col(n, l15) = (n>>1)*256 + w*32 + 2*l15 + (n&1); gate = n>>1; g-gate scale 2*LOG2E.
__global__ __launch_bounds__(64, 1) void xg_table(
    const float* __restrict__ emb,
    const float* __restrict__ Wih,
    const float* __restrict__ bih,
    const float* __restrict__ bhh,
    _Float16*    __restrict__ xgp)
{
    const int L  = threadIdx.x;
    const int l15 = L & 15;
    const int q   = L >> 4;
    const int w   = blockIdx.x & 7;
    const int v0  = (blockIdx.x >> 3) * 64;

    half8 bfr[8][4];
    float bias[8];
    #pragma unroll
    for (int n = 0; n < 8; ++n) {
        const int col = (n >> 1)*256 + w*32 + 2*l15 + (n & 1);
        bias[n] = bih[col] + bhh[col];
        #pragma unroll
        for (int kt = 0; kt < 4; ++kt) {
            const float* p = Wih + col*EDIM + kt*32 + q*8;
            const float4 f0 = *(const float4*)p;
            const float4 f1 = *(const float4*)(p + 4);
            half8 h;
            h[0]=(_Float16)f0.x; h[1]=(_Float16)f0.y; h[2]=(_Float16)f0.z; h[3]=(_Float16)f0.w;
            h[4]=(_Float16)f1.x; h[5]=(_Float16)f1.y; h[6]=(_Float16)f1.z; h[7]=(_Float16)f1.w;
            bfr[n][kt] = h;
        }
    }

    floatx4 acc[4][8];
    #pragma unroll
    for (int mt = 0; mt < 4; ++mt)
        #pragma unroll
        for (int n = 0; n < 8; ++n) acc[mt][n] = (floatx4){0.f,0.f,0.f,0.f};

    #pragma unroll
    for (int mt = 0; mt < 4; ++mt) {
        int v = v0 + mt*16 + l15;
        if (v > NVOCAB-1) v = NVOCAB-1;
        #pragma unroll
        for (int kt = 0; kt < 4; ++kt) {
            const float* p = emb + (size_t)v*EDIM + kt*32 + q*8;
            const float4 f0 = *(const float4*)p;
            const float4 f1 = *(const float4*)(p + 4);
            half8 a;
            a[0]=(_Float16)f0.x; a[1]=(_Float16)f0.y; a[2]=(_Float16)f0.z; a[3]=(_Float16)f0.w;
            a[4]=(_Float16)f1.x; a[5]=(_Float16)f1.y; a[6]=(_Float16)f1.z; a[7]=(_Float16)f1.w;
            #pragma unroll
            for (int n = 0; n < 8; ++n)
                acc[mt][n] = __builtin_amdgcn_mfma_f32_16x16x32_f16(a, bfr[n][kt], acc[mt][n], 0,0,0);
        }
    }

    // store: 16B entry {gates(j0), gates(j0+1)} at v*1024 + (w*16+l15)*8 halfs
    #pragma unroll
    for (int mt = 0; mt < 4; ++mt) {
        #pragma unroll
        for (int r = 0; r < 4; ++r) {
            const int v = v0 + mt*16 + q*4 + r;
            if (v <= NVOCAB-1) {
                union { int4 i4; _Float16 h[8]; } pk;
                #pragma unroll
                for (int g = 0; g < 4; ++g) {
                    const float sc = (g == 2) ? TWO_LOG2E : LOG2E;
                    pk.h[g]     = (_Float16)((acc[mt][2*g  ][r] + bias[2*g  ]) * sc);
                    pk.h[4 + g] = (_Float16)((acc[mt][2*g+1][r] + bias[2*g+1]) * sc);
                }
                *(int4*)(xgp + (size_t)v*1024 + (w*16 + l15)*8) = pk.i4;
            }
        }
    }
}

// Persistent LSTM: 64 blocks x 512 threads (8 waves, r4-proven shape), 4 rows
// per block. A rows aliased (l15&3) => acc element r == batch row r for every
// quad (replicated); lane (l15,q,wv) owns cells (row=q, j=wv*32+2*l15 {+1}).
// Depth-2 prefetch: loop unrolled x2 with disjoint xg regs, so the s_waitcnt
// for an xg load lands 2 steps after issue (round-6 diagnosis: rotation-copy
// forced same-step vmcnt wait -> exposed IC/HBM latency every step).
#define NBLK4   64
#define HS4     272                      // fp8 h row stride (bytes)
#define H8B4    (4*HS4)                  // 1088 per parity
#define SM4_H8   0
#define SM4_HF16 (2*H8B4)                // 2176
#define SM4_RED  (SM4_HF16 + 4*256*2)    // 4224
#define SM4_TOT  (SM4_RED + 64*4)        // 4480

__global__ __launch_bounds__(512, 2) void lstm_table(
    const int*   __restrict__ tok,
    const float* __restrict__ Whh,
    const float* __restrict__ Wout,
    const float* __restrict__ bout,
    const _Float16* __restrict__ xgp,
    float*       __restrict__ out)
{
    __shared__ char smem[SM4_TOT];
    const int tid = threadIdx.x;
    const int wv  = tid >> 6;      // 0..7
    const int L   = tid & 63;
    const int l15 = L & 15;
    const int q   = L >> 4;        // 0..3 = this lane's batch row
    const int g4  = blockIdx.x * 4;
    const int myrow = g4 + q;
    const size_t lane_off = (size_t)(wv*16 + l15)*8;   // xg entry offset (halfs)

    // ---- W_hh fp8 MX fragments: wf[n][kt], 32 B/lane = k in [kt*128+q*32,+32)
    // col(n) = (n>>1)*256 + wv*32 + 2*l15 + (n&1)
    intx8 wf[8][2];
    #pragma unroll
    for (int n = 0; n < 8; ++n) {
        const int col = (n >> 1)*256 + wv*32 + 2*l15 + (n & 1);
        const float sc = ((n >> 1) == 2) ? TWO_LOG2E : LOG2E;
        #pragma unroll
        for (int kt = 0; kt < 2; ++kt) {
            const float* p = Whh + col*HDIM + kt*128 + q*32;
            intx8 v;
            #pragma unroll
            for (int d = 0; d < 8; ++d) {
                const float4 f = *(const float4*)(p + d*4);
                int pk = __builtin_amdgcn_cvt_pk_fp8_f32(f.x*sc, f.y*sc, 0, false);
                pk     = __builtin_amdgcn_cvt_pk_fp8_f32(f.z*sc, f.w*sc, pk, true);
                v[d] = pk;
            }
            wf[n][kt] = v;
        }
    }

    // ---- prefetch pipeline: xgE for even t, xgO for odd t; tokens 2 deep ----
    union Hx { int4 v; _Float16 h[8]; };
    int4 xgE, xgO;
    int tkA, tkB;   // tokens for t+2 (even slot) and t+3 (odd slot)
    xgE = *(const int4*)(xgp + (size_t)tok[myrow]*1024 + lane_off);            // t=0
    xgO = *(const int4*)(xgp + (size_t)tok[NBATCH + myrow]*1024 + lane_off);   // t=1
    tkA = tok[2*NBATCH + myrow];
    tkB = tok[3*NBATCH + myrow];

    float c0 = 0.f, c1 = 0.f;

    // one LSTM sub-step; PAR = t&1 (compile-time per call site)
    auto step = [&](int t, int PAR, int4& xg_slot, int& tk_slot) {
        floatx4 acc[8];
        #pragma unroll
        for (int n = 0; n < 8; ++n) acc[n] = (floatx4){0.f,0.f,0.f,0.f};

        if (t > 0) {
            const char* hb = smem + SM4_H8 + (1-PAR)*H8B4 + (l15 & 3)*HS4 + q*32;
            union { int4 v[2]; intx8 a; } af0, af1;
            af0.v[0] = *(const int4*)(hb);
            af0.v[1] = *(const int4*)(hb + 16);
            af1.v[0] = *(const int4*)(hb + 128);
            af1.v[1] = *(const int4*)(hb + 144);
            #pragma unroll
            for (int n = 0; n < 8; ++n)
                acc[n] = __builtin_amdgcn_mfma_scale_f32_16x16x128_f8f6f4(
                             af0.a, wf[n][0], acc[n], 0, 0, 0, 127, 0, 127);
            #pragma unroll
            for (int n = 0; n < 8; ++n)
                acc[n] = __builtin_amdgcn_mfma_scale_f32_16x16x128_f8f6f4(
                             af1.a, wf[n][1], acc[n], 0, 0, 0, 127, 0, 127);
        }

        // extract element q (rows replicated across quads)
        const bool b0 = (q & 1);
        const bool b1 = (q >= 2);
        float P0[4], P1[4];
        #pragma unroll
        for (int g = 0; g < 4; ++g) {
            float t01 = b0 ? acc[2*g][1] : acc[2*g][0];
            float t23 = b0 ? acc[2*g][3] : acc[2*g][2];
            P0[g] = b1 ? t23 : t01;
            t01 = b0 ? acc[2*g+1][1] : acc[2*g+1][0];
            t23 = b0 ? acc[2*g+1][3] : acc[2*g+1][2];
            P1[g] = b1 ? t23 : t01;
        }
        // consume xg (this is the only read of xg_slot -> vmcnt wait lands here,
        // 2 steps after issue)
        {
            Hx xv; xv.v = xg_slot;
            P0[0] += (float)xv.h[0]; P0[1] += (float)xv.h[1];
            P0[2] += (float)xv.h[2]; P0[3] += (float)xv.h[3];
            P1[0] += (float)xv.h[4]; P1[1] += (float)xv.h[5];
            P1[2] += (float)xv.h[6]; P1[3] += (float)xv.h[7];
        }
        // issue next load into the SAME slot (covers t+2) using tk loaded at t-2
        if (t + 2 < T_STEPS)
            xg_slot = *(const int4*)(xgp + (size_t)tk_slot*1024 + lane_off);
        if (t + 4 < T_STEPS)
            tk_slot = tok[(t+4)*NBATCH + myrow];

        // gates, cell 0 (col j0 = wv*32+2*l15) and cell 1 (j0+1)
        const float iv0 = sigE(P0[0]), fv0 = sigE(P0[1]);
        const float gv0 = tanhE(P0[2]), ov0 = sigE(P0[3]);
        c0 = fv0 * c0 + iv0 * gv0;
        const float h0 = ov0 * tanhE(c0 * TWO_LOG2E);
        const float iv1 = sigE(P1[0]), fv1 = sigE(P1[1]);
        const float gv1 = tanhE(P1[2]), ov1 = sigE(P1[3]);
        c1 = fv1 * c1 + iv1 * gv1;
        const float h1 = ov1 * tanhE(c1 * TWO_LOG2E);

        const int j0 = wv*32 + 2*l15;
        if (t == T_STEPS-1) {
            union { uint32 u; _Float16 h[2]; } hh;
            hh.h[0] = (_Float16)h0; hh.h[1] = (_Float16)h1;
            *(uint32*)(smem + SM4_HF16 + (q*256 + j0)*2) = hh.u;
        } else {
            const int pk = __builtin_amdgcn_cvt_pk_fp8_f32(h0, h1, 0, false);
            *(unsigned short*)(smem + SM4_H8 + PAR*H8B4 + q*HS4 + j0) =
                (unsigned short)(pk & 0xFFFF);
        }
        __syncthreads();
    };

    #pragma unroll 1
    for (int t = 0; t < T_STEPS; t += 2) {
        step(t,     0, xgE, tkA);
        step(t + 1, 1, xgO, tkB);
    }

    // ---- output: y = sigmoid(h_T . W_out + b) for 4 rows ----
    float* red = (float*)(smem + SM4_RED);
    if (tid < 64) {
        const int b = tid >> 4, seg = tid & 15;
        const _Float16* hr = (const _Float16*)(smem + SM4_HF16) + b*256 + seg*16;
        const float* wo = Wout + seg*16;
        float s = 0.f;
        #pragma unroll
        for (int jj = 0; jj < 16; ++jj) s += (float)hr[jj] * wo[jj];
        red[tid] = s;
    }
    __syncthreads();
    if (tid < 4) {
        float s = 0.f;
        #pragma unroll
        for (int k = 0; k < 16; ++k) s += red[tid*16 + k];
        out[g4 + tid] = sigm(s + bout[0]);
    }
}

// ============================================================================
// PATH A (fallback, ws < 102.4 MB): Round-1 kernel (proven, ~8.4 ms)
// ============================================================================
#define FLAGS_OFF   0
#define HBUF_OFF    4096
#define EMB16_OFF   (4096 + 262144)
#define EMB16_BYTES (NVOCAB*EDIM*2)
#define WS_NEED_BIG (EMB16_OFF + EMB16_BYTES)

__global__ void emb_cvt_kernel(const float* __restrict__ src, _Float16* __restrict__ dst, int n4){
    int stride = gridDim.x * blockDim.x;
    for (int i = blockIdx.x*blockDim.x + threadIdx.x; i < n4; i += stride) {
        const float4 v = ((const float4*)src)[i];
        union { _Float16 h[4]; uint2 u; } p;
        p.h[0] = (_Float16)v.x; p.h[1] = (_Float16)v.y;
        p.h[2] = (_Float16)v.z; p.h[3] = (_Float16)v.w;
        ((uint2*)dst)[i] = p.u;
    }
}

__global__ __launch_bounds__(64, 2) void lstm_persist(
    const int*   __restrict__ tok,
    const float* __restrict__ emb32,
    const float* __restrict__ Wih,
    const float* __restrict__ Whh,
    const float* __restrict__ bih,
    const float* __restrict__ bhh,
    const float* __restrict__ Wout,
    const float* __restrict__ bout,
    float*       __restrict__ out,
    char*        __restrict__ ws,
    const _Float16* __restrict__ emb16,
    int use16)
{
    const int L      = threadIdx.x;
    const int lane15 = L & 15;
    const int quad   = L >> 4;
    const int bid    = blockIdx.x;
    const int grp    = (bid & 7)*2 + (bid >> 8);
    const int slc    = (bid >> 3) & 31;

    int*      flags = (int*)(ws + FLAGS_OFF);
    _Float16* hbuf  = (_Float16*)(ws + HBUF_OFF);

    half8 bfr[2][12];
    float bias[2];
    #pragma unroll
    for (int tile = 0; tile < 2; ++tile) {
        const int nloc = tile*16 + lane15;
        const int gate = nloc >> 3;
        const int jj   = nloc & 7;
        const int ng   = gate*HDIM + slc*8 + jj;
        bias[tile] = bih[ng] + bhh[ng];
        #pragma unroll
        for (int kt = 0; kt < 12; ++kt) {
            const int k0 = kt*32 + quad*8;
            const float* p = (kt < 4) ? (Wih + ng*EDIM + k0)
                                      : (Whh + ng*HDIM + (k0 - EDIM));
            half8 h;
            #pragma unroll
            for (int i = 0; i < 8; ++i) h[i] = (_Float16)p[i];
            bfr[tile][kt] = h;
        }
    }

    const int btok = grp*16 + lane15;
    auto ldx = [&](int tk, int kt) -> half8 {
        const int k0 = kt*32 + quad*8;
        if (use16) {
            return *(const half8*)(emb16 + (long)tk*EDIM + k0);
        } else {
            const float* p = emb32 + (long)tk*EDIM + k0;
            half8 h;
            #pragma unroll
            for (int i = 0; i < 8; ++i) h[i] = (_Float16)p[i];
            return h;
        }
    };

    int tok_next = tok[NBATCH + btok];
    half8 xcur[4], xnext[4];
    {
        int tok0 = tok[btok];
        #pragma unroll
        for (int kt = 0; kt < 4; ++kt) xcur[kt] = ldx(tok0, kt);
    }

    float c[4] = {0.f, 0.f, 0.f, 0.f};
    const bool act = (lane15 < 8);
    const bool stl = act && !(lane15 & 1);
    const int  jj8 = lane15 & 7;

    #pragma unroll 1
    for (int t = 0; t < T_STEPS; ++t) {
        if (t + 1 < T_STEPS) {
            #pragma unroll
            for (int kt = 0; kt < 4; ++kt) xnext[kt] = ldx(tok_next, kt);
        }
        int tok_nn = 0;
        if (t + 2 < T_STEPS) tok_nn = tok[(t+2)*NBATCH + btok];

        floatx4 acc0 = {0.f,0.f,0.f,0.f};
        floatx4 acc1 = {0.f,0.f,0.f,0.f};

        #pragma unroll
        for (int kt = 0; kt < 4; ++kt) {
            acc0 = __builtin_amdgcn_mfma_f32_16x16x32_f16(xcur[kt], bfr[0][kt], acc0, 0,0,0);
            acc1 = __builtin_amdgcn_mfma_f32_16x16x32_f16(xcur[kt], bfr[1][kt], acc1, 0,0,0);
        }

        if (t > 0) {
            const int parR = (t-1) & 1;
            int* fl = flags + parR*(NGROUPS*NSLICES) + grp*NSLICES + (L & 31);
            int cnt = 0;
            while (true) {
                int v = __hip_atomic_load(fl, __ATOMIC_RELAXED, __HIP_MEMORY_SCOPE_AGENT);
                if (__all(v >= t)) break;
                if (++cnt > (1<<15)) break;
                __builtin_amdgcn_s_sleep(1);
            }
            asm volatile("" ::: "memory");
            const _Float16* hr = hbuf + (parR*NGROUPS + grp)*(16*HDIM) + lane15*HDIM;
            #pragma unroll
            for (int kt = 4; kt < 12; ++kt) {
                const int j0 = (kt-4)*32 + quad*8;
                const uint32* hp = (const uint32*)(hr + j0);
                union { uint32 u[4]; half8 h; } hf;
                hf.u[0] = __hip_atomic_load(hp+0, __ATOMIC_RELAXED, __HIP_MEMORY_SCOPE_AGENT);
                hf.u[1] = __hip_atomic_load(hp+1, __ATOMIC_RELAXED, __HIP_MEMORY_SCOPE_AGENT);
                hf.u[2] = __hip_atomic_load(hp+2, __ATOMIC_RELAXED, __HIP_MEMORY_SCOPE_AGENT);
                hf.u[3] = __hip_atomic_load(hp+3, __ATOMIC_RELAXED, __HIP_MEMORY_SCOPE_AGENT);
                acc0 = __builtin_amdgcn_mfma_f32_16x16x32_f16(hf.h, bfr[0][kt], acc0, 0,0,0);
                acc1 = __builtin_amdgcn_mfma_f32_16x16x32_f16(hf.h, bfr[1][kt], acc1, 0,0,0);
            }
        }

        uint32 hdw[4];
        #pragma unroll
        for (int r = 0; r < 4; ++r) {
            float p0 = acc0[r] + bias[0];
            float p1 = acc1[r] + bias[1];
            float fpre = __int_as_float(__builtin_amdgcn_ds_swizzle(__float_as_int(p0), 0x201F));
            float opre = __int_as_float(__builtin_amdgcn_ds_swizzle(__float_as_int(p1), 0x201F));
            float iv = sigm(p0);
            float fv = sigm(fpre);
            float gv = tanh_fast(p1);
            float ov = sigm(opre);
            float cn = fv * c[r] + iv * gv;
            c[r] = cn;
            float hv = ov * tanh_fast(cn);
            union { _Float16 f; unsigned short u; } cvh; cvh.f = (_Float16)hv;
            uint32 hu = cvh.u;
            uint32 part = (uint32)__builtin_amdgcn_ds_swizzle((int)hu, 0x041F);
            hdw[r] = (hu & 0xFFFFu) | (part << 16);
        }
        {
            _Float16* hwb = hbuf + (((t&1)*NGROUPS) + grp)*(16*HDIM);
            if (stl) {
                #pragma unroll
                for (int r = 0; r < 4; ++r) {
                    const int m = quad*4 + r;
                    uint32* dst = (uint32*)(hwb + m*HDIM + slc*8 + jj8);
                    __hip_atomic_store(dst, hdw[r], __ATOMIC_RELAXED, __HIP_MEMORY_SCOPE_AGENT);
                }
            }
            asm volatile("s_waitcnt vmcnt(0)" ::: "memory");
            if (L == 0) {
                int* myf = flags + (t&1)*(NGROUPS*NSLICES) + grp*NSLICES + slc;
                __hip_atomic_store(myf, t+1, __ATOMIC_RELAXED, __HIP_MEMORY_SCOPE_AGENT);
            }
        }
        #pragma unroll
        for (int kt = 0; kt < 4; ++kt) xcur[kt] = xnext[kt];
        tok_next = tok_nn;
    }

    if (slc == 0) {
        const int parF = (T_STEPS-1) & 1;
        int* fl = flags + parF*(NGROUPS*NSLICES) + grp*NSLICES + (L & 31);
        int cnt = 0;
        while (true) {
            int v = __hip_atomic_load(fl, __ATOMIC_RELAXED, __HIP_MEMORY_SCOPE_AGENT);
            if (__all(v >= T_STEPS)) break;
            if (++cnt > (1<<15)) break;
            __builtin_amdgcn_s_sleep(1);
        }
        asm volatile("" ::: "memory");
        const int m  = L >> 2;
        const int pp = L & 3;
        const _Float16* hr = hbuf + (parF*NGROUPS + grp)*(16*HDIM) + m*HDIM;
        const uint32* hp = (const uint32*)hr + pp*32;
        float sum = 0.f;
        #pragma unroll
        for (int d = 0; d < 32; ++d) {
            uint32 u = __hip_atomic_load(hp + d, __ATOMIC_RELAXED, __HIP_MEMORY_SCOPE_AGENT);
            union { uint32 u; _Float16 h[2]; } cv; cv.u = u;
            const int j = pp*64 + d*2;
            sum += (float)cv.h[0] * Wout[j] + (float)cv.h[1] * Wout[j+1];
        }
        sum += __int_as_float(__builtin_amdgcn_ds_swizzle(__float_as_int(sum), 0x041F));
        sum += __int_as_float(__builtin_amdgcn_ds_swizzle(__float_as_int(sum), 0x081F));
        if (pp == 0) out[grp*16 + m] = sigm(sum + bout[0]);
    }
}

// ============================================================================
extern "C" void kernel_launch(void* const* d_in, const int* in_sizes, int n_in,
                              void* d_out, int out_size, void* d_ws, size_t ws_size,
                              hipStream_t stream) {
    const int*   tokp = (const int*)  d_in[0];
    const float* emb  = (const float*)d_in[1];
    const float* Wih  = (const float*)d_in[2];
    const float* Whh  = (const float*)d_in[3];
    const float* bih  = (const float*)d_in[4];
    const float* bhh  = (const float*)d_in[5];
    const float* Wout = (const float*)d_in[6];
    const float* bout = (const float*)d_in[7];
    float* out = (float*)d_out;
    char*  ws  = (char*)d_ws;

    if (ws_size >= TABLE_BYTES) {
        _Float16* xgp = (_Float16*)ws;
        const int vtiles = (NVOCAB + 63) / 64;          // 782
        xg_table<<<vtiles*8, 64, 0, stream>>>(emb, Wih, bih, bhh, xgp);
        lstm_table<<<NBLK4, 512, 0, stream>>>(tokp, Whh, Wout, bout, xgp, out);
    } else {
        const int use16 = (ws_size >= (size_t)WS_NEED_BIG) ? 1 : 0;
        _Float16* emb16 = (_Float16*)(ws + EMB16_OFF);
        if (use16) {
            emb_cvt_kernel<<<1024, 256, 0, stream>>>(emb, emb16, NVOCAB*EDIM/4);
        }
        lstm_persist<<<NBLOCKS, 64, 0, stream>>>(tokp, emb, Wih, Whh, bih, bhh, Wout, bout,
                                                 out, ws, emb16, use16);
    }
}

// Round 8
// 1934.673 us; speedup vs baseline: 2.8585x; 1.1491x over previous
//
#include <hip/hip_runtime.h>

#define T_STEPS 2048
#define NBATCH  256
#define EDIM    128
#define HDIM    256
#define NVOCAB  50001
#define NGROUPS 16
#define NSLICES 32
#define NBLOCKS (NGROUPS*NSLICES)

typedef _Float16 half8 __attribute__((ext_vector_type(8)));
typedef float    floatx4 __attribute__((ext_vector_type(4)));
typedef int      intx8  __attribute__((ext_vector_type(8)));
typedef unsigned int uint32;

#define LOG2E      1.4426950408889634f
#define TWO_LOG2E  2.8853900817779268f

__device__ __forceinline__ float sigE(float x){   // x = LOG2E * z ; returns sigmoid(z)
    return __builtin_amdgcn_rcpf(1.0f + __builtin_amdgcn_exp2f(-x));
}
__device__ __forceinline__ float tanhE(float x){  // x = 2*LOG2E * z ; returns tanh(z)
    return 2.0f * __builtin_amdgcn_rcpf(1.0f + __builtin_amdgcn_exp2f(-x)) - 1.0f;
}
__device__ __forceinline__ float sigm(float x){ return 1.0f/(1.0f + __expf(-x)); }
__device__ __forceinline__ float tanh_fast(float x){ return 2.0f/(1.0f + __expf(-2.0f*x)) - 1.0f; }

// ============================================================================
// PATH B (ws >= 102.4 MB): xg vocab table (pre-scaled, [v][j][4 gates] f16) +
// 128-CU persistent LSTM (2 rows/CU, 1 cell/lane), depth-2 slotted prefetch,
// MX K=128 fp8 recurrent MFMA.
// ============================================================================
#define TABLE_BYTES ((size_t)NVOCAB * 1024 * 2)   // 102,402,048

// xg_table: entry(v, j) = 4 f16 {i,f,g,o} at xgp + v*1024 + j*4 (halfs).
// Writer stores pairs {gates(j0), gates(j0+1)} as one 16B int4 (byte offset
// v*2048 + j0*8, j0 = w*32+2*l15) — bit-identical to addressing j*8 bytes.
__global__ __launch_bounds__(64, 1) void xg_table(
    const float* __restrict__ emb,
    const float* __restrict__ Wih,
    const float* __restrict__ bih,
    const float* __restrict__ bhh,
    _Float16*    __restrict__ xgp)
{
    const int L  = threadIdx.x;
    const int l15 = L & 15;
    const int q   = L >> 4;
    const int w   = blockIdx.x & 7;
    const int v0  = (blockIdx.x >> 3) * 64;

    half8 bfr[8][4];
    float bias[8];
    #pragma unroll
    for (int n = 0; n < 8; ++n) {
        const int col = (n >> 1)*256 + w*32 + 2*l15 + (n & 1);
        bias[n] = bih[col] + bhh[col];
        #pragma unroll
        for (int kt = 0; kt < 4; ++kt) {
            const float* p = Wih + col*EDIM + kt*32 + q*8;
            const float4 f0 = *(const float4*)p;
            const float4 f1 = *(const float4*)(p + 4);
            half8 h;
            h[0]=(_Float16)f0.x; h[1]=(_Float16)f0.y; h[2]=(_Float16)f0.z; h[3]=(_Float16)f0.w;
            h[4]=(_Float16)f1.x; h[5]=(_Float16)f1.y; h[6]=(_Float16)f1.z; h[7]=(_Float16)f1.w;
            bfr[n][kt] = h;
        }
    }

    floatx4 acc[4][8];
    #pragma unroll
    for (int mt = 0; mt < 4; ++mt)
        #pragma unroll
        for (int n = 0; n < 8; ++n) acc[mt][n] = (floatx4){0.f,0.f,0.f,0.f};

    #pragma unroll
    for (int mt = 0; mt < 4; ++mt) {
        int v = v0 + mt*16 + l15;
        if (v > NVOCAB-1) v = NVOCAB-1;
        #pragma unroll
        for (int kt = 0; kt < 4; ++kt) {
            const float* p = emb + (size_t)v*EDIM + kt*32 + q*8;
            const float4 f0 = *(const float4*)p;
            const float4 f1 = *(const float4*)(p + 4);
            half8 a;
            a[0]=(_Float16)f0.x; a[1]=(_Float16)f0.y; a[2]=(_Float16)f0.z; a[3]=(_Float16)f0.w;
            a[4]=(_Float16)f1.x; a[5]=(_Float16)f1.y; a[6]=(_Float16)f1.z; a[7]=(_Float16)f1.w;
            #pragma unroll
            for (int n = 0; n < 8; ++n)
                acc[mt][n] = __builtin_amdgcn_mfma_f32_16x16x32_f16(a, bfr[n][kt], acc[mt][n], 0,0,0);
        }
    }

    #pragma unroll
    for (int mt = 0; mt < 4; ++mt) {
        #pragma unroll
        for (int r = 0; r < 4; ++r) {
            const int v = v0 + mt*16 + q*4 + r;
            if (v <= NVOCAB-1) {
                union { int4 i4; _Float16 h[8]; } pk;
                #pragma unroll
                for (int g = 0; g < 4; ++g) {
                    const float sc = (g == 2) ? TWO_LOG2E : LOG2E;
                    pk.h[g]     = (_Float16)((acc[mt][2*g  ][r] + bias[2*g  ]) * sc);
                    pk.h[4 + g] = (_Float16)((acc[mt][2*g+1][r] + bias[2*g+1]) * sc);
                }
                *(int4*)(xgp + (size_t)v*1024 + (w*16 + l15)*8) = pk.i4;
            }
        }
    }
}

// Persistent LSTM: 128 blocks x 512 threads (8 waves), 2 batch rows per block,
// exactly 1 cell per lane. A rows aliased (l15&1) => acc element r holds batch
// row (r&1) for every quad; lane (wv,l15,q) owns row=q&1, j=wv*32+2*l15+(q>>1),
// extracted as acc[2g+jo][row] (cndmask only, no shuffles).
// Depth-2 slotted xg prefetch (r7-proven): a load issued at t is first waited
// on at t+2.
#define NBLK5   128
#define HS5     272                      // fp8 h row stride (bytes)
#define H8B5    (2*HS5)                  // 544 per parity
#define SM5_H8   0
#define SM5_HF16 (2*H8B5)                // 1088
#define SM5_RED  (SM5_HF16 + 2*256*2)    // 2112
#define SM5_TOT  (SM5_RED + 32*4)        // 2240

__global__ __launch_bounds__(512, 2) void lstm_table(
    const int*   __restrict__ tok,
    const float* __restrict__ Whh,
    const float* __restrict__ Wout,
    const float* __restrict__ bout,
    const _Float16* __restrict__ xgp,
    float*       __restrict__ out)
{
    __shared__ char smem[SM5_TOT];
    const int tid = threadIdx.x;
    const int wv  = tid >> 6;      // 0..7
    const int L   = tid & 63;
    const int l15 = L & 15;
    const int q   = L >> 4;        // row = q&1, jo = q>>1
    const int row = q & 1;
    const int jo  = q >> 1;
    const int g2  = blockIdx.x * 2;
    const int myrow = g2 + row;
    const int jme   = wv*32 + 2*l15 + jo;            // this lane's H column
    const size_t lane_off = (size_t)jme * 4;         // xg entry offset (halfs)

    // ---- W_hh fp8 MX fragments: wf[n][kt], 32 B/lane = k in [kt*128+q*32,+32)
    // B col of tile n at lane l15: (n>>1)*256 + wv*32 + 2*l15 + (n&1)
    intx8 wf[8][2];
    #pragma unroll
    for (int n = 0; n < 8; ++n) {
        const int col = (n >> 1)*256 + wv*32 + 2*l15 + (n & 1);
        const float sc = ((n >> 1) == 2) ? TWO_LOG2E : LOG2E;
        #pragma unroll
        for (int kt = 0; kt < 2; ++kt) {
            const float* p = Whh + col*HDIM + kt*128 + q*32;
            intx8 v;
            #pragma unroll
            for (int d = 0; d < 8; ++d) {
                const float4 f = *(const float4*)(p + d*4);
                int pk = __builtin_amdgcn_cvt_pk_fp8_f32(f.x*sc, f.y*sc, 0, false);
                pk     = __builtin_amdgcn_cvt_pk_fp8_f32(f.z*sc, f.w*sc, pk, true);
                v[d] = pk;
            }
            wf[n][kt] = v;
        }
    }

    // ---- prefetch pipeline: xgE for even t, xgO for odd t; tokens 2 deep ----
    union Hx { uint2 v; _Float16 h[4]; };
    uint2 xgE, xgO;
    int tkA, tkB;
    xgE = *(const uint2*)(xgp + (size_t)tok[myrow]*1024 + lane_off);            // t=0
    xgO = *(const uint2*)(xgp + (size_t)tok[NBATCH + myrow]*1024 + lane_off);   // t=1
    tkA = tok[2*NBATCH + myrow];
    tkB = tok[3*NBATCH + myrow];

    float c = 0.f;

    auto step = [&](int t, int PAR, uint2& xg_slot, int& tk_slot) {
        floatx4 acc[8];
        #pragma unroll
        for (int n = 0; n < 8; ++n) acc[n] = (floatx4){0.f,0.f,0.f,0.f};

        if (t > 0) {
            const char* hb = smem + SM5_H8 + (1-PAR)*H8B5 + (l15 & 1)*HS5 + q*32;
            union { int4 v[2]; intx8 a; } af0, af1;
            af0.v[0] = *(const int4*)(hb);
            af0.v[1] = *(const int4*)(hb + 16);
            af1.v[0] = *(const int4*)(hb + 128);
            af1.v[1] = *(const int4*)(hb + 144);
            #pragma unroll
            for (int n = 0; n < 8; ++n)
                acc[n] = __builtin_amdgcn_mfma_scale_f32_16x16x128_f8f6f4(
                             af0.a, wf[n][0], acc[n], 0, 0, 0, 127, 0, 127);
            #pragma unroll
            for (int n = 0; n < 8; ++n)
                acc[n] = __builtin_amdgcn_mfma_scale_f32_16x16x128_f8f6f4(
                             af1.a, wf[n][1], acc[n], 0, 0, 0, 127, 0, 127);
        }

        // extract this lane's cell: gate g at acc[2g+jo][row] (row in {0,1})
        float P[4];
        #pragma unroll
        for (int g = 0; g < 4; ++g) {
            const float e0 = row ? acc[2*g  ][1] : acc[2*g  ][0];
            const float e1 = row ? acc[2*g+1][1] : acc[2*g+1][0];
            P[g] = jo ? e1 : e0;
        }
        // consume xg (only read of xg_slot -> vmcnt wait lands 2 steps after issue)
        {
            Hx xv; xv.v = xg_slot;
            P[0] += (float)xv.h[0]; P[1] += (float)xv.h[1];
            P[2] += (float)xv.h[2]; P[3] += (float)xv.h[3];
        }
        // refill the SAME slot for t+2
        if (t + 2 < T_STEPS)
            xg_slot = *(const uint2*)(xgp + (size_t)tk_slot*1024 + lane_off);
        if (t + 4 < T_STEPS)
            tk_slot = tok[(t+4)*NBATCH + myrow];

        const float iv = sigE(P[0]), fv = sigE(P[1]);
        const float gv = tanhE(P[2]), ov = sigE(P[3]);
        c = fv * c + iv * gv;
        const float hv = ov * tanhE(c * TWO_LOG2E);

        if (t == T_STEPS-1) {
            *(_Float16*)(smem + SM5_HF16 + (row*256 + jme)*2) = (_Float16)hv;
        } else {
            const int pk = __builtin_amdgcn_cvt_pk_fp8_f32(hv, hv, 0, false);
            *(char*)(smem + SM5_H8 + PAR*H8B5 + row*HS5 + jme) = (char)(pk & 0xFF);
        }
        __syncthreads();
    };

    #pragma unroll 1
    for (int t = 0; t < T_STEPS; t += 2) {
        step(t,     0, xgE, tkA);
        step(t + 1, 1, xgO, tkB);
    }

    // ---- output: y = sigmoid(h_T . W_out + b) for 2 rows ----
    float* red = (float*)(smem + SM5_RED);
    if (tid < 32) {
        const int b = tid >> 4, seg = tid & 15;
        const _Float16* hr = (const _Float16*)(smem + SM5_HF16) + b*256 + seg*16;
        const float* wo = Wout + seg*16;
        float s = 0.f;
        #pragma unroll
        for (int jj = 0; jj < 16; ++jj) s += (float)hr[jj] * wo[jj];
        red[tid] = s;
    }
    __syncthreads();
    if (tid < 2) {
        float s = 0.f;
        #pragma unroll
        for (int k = 0; k < 16; ++k) s += red[tid*16 + k];
        out[g2 + tid] = sigm(s + bout[0]);
    }
}

// ============================================================================
// PATH A (fallback, ws < 102.4 MB): Round-1 kernel (proven, ~8.4 ms)
// ============================================================================
#define FLAGS_OFF   0
#define HBUF_OFF    4096
#define EMB16_OFF   (4096 + 262144)
#define EMB16_BYTES (NVOCAB*EDIM*2)
#define WS_NEED_BIG (EMB16_OFF + EMB16_BYTES)

__global__ void emb_cvt_kernel(const float* __restrict__ src, _Float16* __restrict__ dst, int n4){
    int stride = gridDim.x * blockDim.x;
    for (int i = blockIdx.x*blockDim.x + threadIdx.x; i < n4; i += stride) {
        const float4 v = ((const float4*)src)[i];
        union { _Float16 h[4]; uint2 u; } p;
        p.h[0] = (_Float16)v.x; p.h[1] = (_Float16)v.y;
        p.h[2] = (_Float16)v.z; p.h[3] = (_Float16)v.w;
        ((uint2*)dst)[i] = p.u;
    }
}

__global__ __launch_bounds__(64, 2) void lstm_persist(
    const int*   __restrict__ tok,
    const float* __restrict__ emb32,
    const float* __restrict__ Wih,
    const float* __restrict__ Whh,
    const float* __restrict__ bih,
    const float* __restrict__ bhh,
    const float* __restrict__ Wout,
    const float* __restrict__ bout,
    float*       __restrict__ out,
    char*        __restrict__ ws,
    const _Float16* __restrict__ emb16,
    int use16)
{
    const int L      = threadIdx.x;
    const int lane15 = L & 15;
    const int quad   = L >> 4;
    const int bid    = blockIdx.x;
    const int grp    = (bid & 7)*2 + (bid >> 8);
    const int slc    = (bid >> 3) & 31;

    int*      flags = (int*)(ws + FLAGS_OFF);
    _Float16* hbuf  = (_Float16*)(ws + HBUF_OFF);

    half8 bfr[2][12];
    float bias[2];
    #pragma unroll
    for (int tile = 0; tile < 2; ++tile) {
        const int nloc = tile*16 + lane15;
        const int gate = nloc >> 3;
        const int jj   = nloc & 7;
        const int ng   = gate*HDIM + slc*8 + jj;
        bias[tile] = bih[ng] + bhh[ng];
        #pragma unroll
        for (int kt = 0; kt < 12; ++kt) {
            const int k0 = kt*32 + quad*8;
            const float* p = (kt < 4) ? (Wih + ng*EDIM + k0)
                                      : (Whh + ng*HDIM + (k0 - EDIM));
            half8 h;
            #pragma unroll
            for (int i = 0; i < 8; ++i) h[i] = (_Float16)p[i];
            bfr[tile][kt] = h;
        }
    }

    const int btok = grp*16 + lane15;
    auto ldx = [&](int tk, int kt) -> half8 {
        const int k0 = kt*32 + quad*8;
        if (use16) {
            return *(const half8*)(emb16 + (long)tk*EDIM + k0);
        } else {
            const float* p = emb32 + (long)tk*EDIM + k0;
            half8 h;
            #pragma unroll
            for (int i = 0; i < 8; ++i) h[i] = (_Float16)p[i];
            return h;
        }
    };

    int tok_next = tok[NBATCH + btok];
    half8 xcur[4], xnext[4];
    {
        int tok0 = tok[btok];
        #pragma unroll
        for (int kt = 0; kt < 4; ++kt) xcur[kt] = ldx(tok0, kt);
    }

    float c[4] = {0.f, 0.f, 0.f, 0.f};
    const bool act = (lane15 < 8);
    const bool stl = act && !(lane15 & 1);
    const int  jj8 = lane15 & 7;

    #pragma unroll 1
    for (int t = 0; t < T_STEPS; ++t) {
        if (t + 1 < T_STEPS) {
            #pragma unroll
            for (int kt = 0; kt < 4; ++kt) xnext[kt] = ldx(tok_next, kt);
        }
        int tok_nn = 0;
        if (t + 2 < T_STEPS) tok_nn = tok[(t+2)*NBATCH + btok];

        floatx4 acc0 = {0.f,0.f,0.f,0.f};
        floatx4 acc1 = {0.f,0.f,0.f,0.f};

        #pragma unroll
        for (int kt = 0; kt < 4; ++kt) {
            acc0 = __builtin_amdgcn_mfma_f32_16x16x32_f16(xcur[kt], bfr[0][kt], acc0, 0,0,0);
            acc1 = __builtin_amdgcn_mfma_f32_16x16x32_f16(xcur[kt], bfr[1][kt], acc1, 0,0,0);
        }

        if (t > 0) {
            const int parR = (t-1) & 1;
            int* fl = flags + parR*(NGROUPS*NSLICES) + grp*NSLICES + (L & 31);
            int cnt = 0;
            while (true) {
                int v = __hip_atomic_load(fl, __ATOMIC_RELAXED, __HIP_MEMORY_SCOPE_AGENT);
                if (__all(v >= t)) break;
                if (++cnt > (1<<15)) break;
                __builtin_amdgcn_s_sleep(1);
            }
            asm volatile("" ::: "memory");
            const _Float16* hr = hbuf + (parR*NGROUPS + grp)*(16*HDIM) + lane15*HDIM;
            #pragma unroll
            for (int kt = 4; kt < 12; ++kt) {
                const int j0 = (kt-4)*32 + quad*8;
                const uint32* hp = (const uint32*)(hr + j0);
                union { uint32 u[4]; half8 h; } hf;
                hf.u[0] = __hip_atomic_load(hp+0, __ATOMIC_RELAXED, __HIP_MEMORY_SCOPE_AGENT);
                hf.u[1] = __hip_atomic_load(hp+1, __ATOMIC_RELAXED, __HIP_MEMORY_SCOPE_AGENT);
                hf.u[2] = __hip_atomic_load(hp+2, __ATOMIC_RELAXED, __HIP_MEMORY_SCOPE_AGENT);
                hf.u[3] = __hip_atomic_load(hp+3, __ATOMIC_RELAXED, __HIP_MEMORY_SCOPE_AGENT);
                acc0 = __builtin_amdgcn_mfma_f32_16x16x32_f16(hf.h, bfr[0][kt], acc0, 0,0,0);
                acc1 = __builtin_amdgcn_mfma_f32_16x16x32_f16(hf.h, bfr[1][kt], acc1, 0,0,0);
            }
        }

        uint32 hdw[4];
        #pragma unroll
        for (int r = 0; r < 4; ++r) {
            float p0 = acc0[r] + bias[0];
            float p1 = acc1[r] + bias[1];
            float fpre = __int_as_float(__builtin_amdgcn_ds_swizzle(__float_as_int(p0), 0x201F));
            float opre = __int_as_float(__builtin_amdgcn_ds_swizzle(__float_as_int(p1), 0x201F));
            float iv = sigm(p0);
            float fv = sigm(fpre);
            float gv = tanh_fast(p1);
            float ov = sigm(opre);
            float cn = fv * c[r] + iv * gv;
            c[r] = cn;
            float hv = ov * tanh_fast(cn);
            union { _Float16 f; unsigned short u; } cvh; cvh.f = (_Float16)hv;
            uint32 hu = cvh.u;
            uint32 part = (uint32)__builtin_amdgcn_ds_swizzle((int)hu, 0x041F);
            hdw[r] = (hu & 0xFFFFu) | (part << 16);
        }
        {
            _Float16* hwb = hbuf + (((t&1)*NGROUPS) + grp)*(16*HDIM);
            if (stl) {
                #pragma unroll
                for (int r = 0; r < 4; ++r) {
                    const int m = quad*4 + r;
                    uint32* dst = (uint32*)(hwb + m*HDIM + slc*8 + jj8);
                    __hip_atomic_store(dst, hdw[r], __ATOMIC_RELAXED, __HIP_MEMORY_SCOPE_AGENT);
                }
            }
            asm volatile("s_waitcnt vmcnt(0)" ::: "memory");
            if (L == 0) {
                int* myf = flags + (t&1)*(NGROUPS*NSLICES) + grp*NSLICES + slc;
                __hip_atomic_store(myf, t+1, __ATOMIC_RELAXED, __HIP_MEMORY_SCOPE_AGENT);
            }
        }
        #pragma unroll
        for (int kt = 0; kt < 4; ++kt) xcur[kt] = xnext[kt];
        tok_next = tok_nn;
    }

    if (slc == 0) {
        const int parF = (T_STEPS-1) & 1;
        int* fl = flags + parF*(NGROUPS*NSLICES) + grp*NSLICES + (L & 31);
        int cnt = 0;
        while (true) {
            int v = __hip_atomic_load(fl, __ATOMIC_RELAXED, __HIP_MEMORY_SCOPE_AGENT);
            if (__all(v >= T_STEPS)) break;
            if (++cnt > (1<<15)) break;
            __builtin_amdgcn_s_sleep(1);
        }
        asm volatile("" ::: "memory");
        const int m  = L >> 2;
        const int pp = L & 3;
        const _Float16* hr = hbuf + (parF*NGROUPS + grp)*(16*HDIM) + m*HDIM;
        const uint32* hp = (const uint32*)hr + pp*32;
        float sum = 0.f;
        #pragma unroll
        for (int d = 0; d < 32; ++d) {
            uint32 u = __hip_atomic_load(hp + d, __ATOMIC_RELAXED, __HIP_MEMORY_SCOPE_AGENT);
            union { uint32 u; _Float16 h[2]; } cv; cv.u = u;
            const int j = pp*64 + d*2;
            sum += (float)cv.h[0] * Wout[j] + (float)cv.h[1] * Wout[j+1];
        }
        sum += __int_as_float(__builtin_amdgcn_ds_swizzle(__float_as_int(sum), 0x041F));
        sum += __int_as_float(__builtin_amdgcn_ds_swizzle(__float_as_int(sum), 0x081F));
        if (pp == 0) out[grp*16 + m] = sigm(sum + bout[0]);
    }
}

// ============================================================================
extern "C" void kernel_launch(void* const* d_in, const int* in_sizes, int n_in,
                              void* d_out, int out_size, void* d_ws, size_t ws_size,
                              hipStream_t stream) {
    const int*   tokp = (const int*)  d_in[0];
    const float* emb  = (const float*)d_in[1];
    const float* Wih  = (const float*)d_in[2];
    const float* Whh  = (const float*)d_in[3];
    const float* bih  = (const float*)d_in[4];
    const float* bhh  = (const float*)d_in[5];
    const float* Wout = (const float*)d_in[6];
    const float* bout = (const float*)d_in[7];
    float* out = (float*)d_out;
    char*  ws  = (char*)d_ws;

    if (ws_size >= TABLE_BYTES) {
        _Float16* xgp = (_Float16*)ws;
        const int vtiles = (NVOCAB + 63) / 64;          // 782
        xg_table<<<vtiles*8, 64, 0, stream>>>(emb, Wih, bih, bhh, xgp);
        lstm_table<<<NBLK5, 512, 0, stream>>>(tokp, Whh, Wout, bout, xgp, out);
    } else {
        const int use16 = (ws_size >= (size_t)WS_NEED_BIG) ? 1 : 0;
        _Float16* emb16 = (_Float16*)(ws + EMB16_OFF);
        if (use16) {
            emb_cvt_kernel<<<1024, 256, 0, stream>>>(emb, emb16, NVOCAB*EDIM/4);
        }
        lstm_persist<<<NBLOCKS, 64, 0, stream>>>(tokp, emb, Wih, Whh, bih, bhh, Wout, bout,
                                                 out, ws, emb16, use16);
    }
}

// Round 9
// 1734.650 us; speedup vs baseline: 3.1881x; 1.1153x over previous
//
#include <hip/hip_runtime.h>

#define T_STEPS 2048
#define NBATCH  256
#define EDIM    128
#define HDIM    256
#define NVOCAB  50001
#define NGROUPS 16
#define NSLICES 32
#define NBLOCKS (NGROUPS*NSLICES)

typedef _Float16 half8 __attribute__((ext_vector_type(8)));
typedef float    floatx4 __attribute__((ext_vector_type(4)));
typedef int      intx8  __attribute__((ext_vector_type(8)));
typedef unsigned int uint32;

#define LOG2E      1.4426950408889634f
#define TWO_LOG2E  2.8853900817779268f

__device__ __forceinline__ float sigE(float x){   // x = LOG2E * z ; returns sigmoid(z)
    return __builtin_amdgcn_rcpf(1.0f + __builtin_amdgcn_exp2f(-x));
}
__device__ __forceinline__ float tanhE(float x){  // x = 2*LOG2E * z ; returns tanh(z)
    return 2.0f * __builtin_amdgcn_rcpf(1.0f + __builtin_amdgcn_exp2f(-x)) - 1.0f;
}
__device__ __forceinline__ float sigm(float x){ return 1.0f/(1.0f + __expf(-x)); }
__device__ __forceinline__ float tanh_fast(float x){ return 2.0f/(1.0f + __expf(-2.0f*x)) - 1.0f; }

// ============================================================================
// PATH B (ws >= 102.4 MB): xg vocab table (pre-scaled, [v][j][4 gates] f16) +
// 128-CU persistent LSTM (2 rows/CU, 1 cell/lane), depth-4 slotted prefetch
// (refill issued immediately after consumption so the __syncthreads vmcnt(0)
// drain completes for free), MX K=128 fp8 recurrent MFMA.
// ============================================================================
#define TABLE_BYTES ((size_t)NVOCAB * 1024 * 2)   // 102,402,048

__global__ __launch_bounds__(64, 1) void xg_table(
    const float* __restrict__ emb,
    const float* __restrict__ Wih,
    const float* __restrict__ bih,
    const float* __restrict__ bhh,
    _Float16*    __restrict__ xgp)
{
    const int L  = threadIdx.x;
    const int l15 = L & 15;
    const int q   = L >> 4;
    const int w   = blockIdx.x & 7;
    const int v0  = (blockIdx.x >> 3) * 64;

    half8 bfr[8][4];
    float bias[8];
    #pragma unroll
    for (int n = 0; n < 8; ++n) {
        const int col = (n >> 1)*256 + w*32 + 2*l15 + (n & 1);
        bias[n] = bih[col] + bhh[col];
        #pragma unroll
        for (int kt = 0; kt < 4; ++kt) {
            const float* p = Wih + col*EDIM + kt*32 + q*8;
            const float4 f0 = *(const float4*)p;
            const float4 f1 = *(const float4*)(p + 4);
            half8 h;
            h[0]=(_Float16)f0.x; h[1]=(_Float16)f0.y; h[2]=(_Float16)f0.z; h[3]=(_Float16)f0.w;
            h[4]=(_Float16)f1.x; h[5]=(_Float16)f1.y; h[6]=(_Float16)f1.z; h[7]=(_Float16)f1.w;
            bfr[n][kt] = h;
        }
    }

    floatx4 acc[4][8];
    #pragma unroll
    for (int mt = 0; mt < 4; ++mt)
        #pragma unroll
        for (int n = 0; n < 8; ++n) acc[mt][n] = (floatx4){0.f,0.f,0.f,0.f};

    #pragma unroll
    for (int mt = 0; mt < 4; ++mt) {
        int v = v0 + mt*16 + l15;
        if (v > NVOCAB-1) v = NVOCAB-1;
        #pragma unroll
        for (int kt = 0; kt < 4; ++kt) {
            const float* p = emb + (size_t)v*EDIM + kt*32 + q*8;
            const float4 f0 = *(const float4*)p;
            const float4 f1 = *(const float4*)(p + 4);
            half8 a;
            a[0]=(_Float16)f0.x; a[1]=(_Float16)f0.y; a[2]=(_Float16)f0.z; a[3]=(_Float16)f0.w;
            a[4]=(_Float16)f1.x; a[5]=(_Float16)f1.y; a[6]=(_Float16)f1.z; a[7]=(_Float16)f1.w;
            #pragma unroll
            for (int n = 0; n < 8; ++n)
                acc[mt][n] = __builtin_amdgcn_mfma_f32_16x16x32_f16(a, bfr[n][kt], acc[mt][n], 0,0,0);
        }
    }

    #pragma unroll
    for (int mt = 0; mt < 4; ++mt) {
        #pragma unroll
        for (int r = 0; r < 4; ++r) {
            const int v = v0 + mt*16 + q*4 + r;
            if (v <= NVOCAB-1) {
                union { int4 i4; _Float16 h[8]; } pk;
                #pragma unroll
                for (int g = 0; g < 4; ++g) {
                    const float sc = (g == 2) ? TWO_LOG2E : LOG2E;
                    pk.h[g]     = (_Float16)((acc[mt][2*g  ][r] + bias[2*g  ]) * sc);
                    pk.h[4 + g] = (_Float16)((acc[mt][2*g+1][r] + bias[2*g+1]) * sc);
                }
                *(int4*)(xgp + (size_t)v*1024 + (w*16 + l15)*8) = pk.i4;
            }
        }
    }
}

// Persistent LSTM: 128 blocks x 512 threads (8 waves), 2 batch rows per block,
// 1 cell per lane (r8-proven). Depth-4 slotted xg prefetch: slot consumed at t,
// refilled immediately for t+4 -> the end-of-step vmcnt(0) barrier drain finds
// the load ~1600+ cyc in flight (r8 diagnosis: mid-step-issued refill was
// drained by __syncthreads with ~500 cyc exposed HBM latency every step).
#define NBLK5   128
#define HS5     272                      // fp8 h row stride (bytes)
#define H8B5    (2*HS5)                  // 544 per parity
#define SM5_H8   0
#define SM5_HF16 (2*H8B5)                // 1088
#define SM5_RED  (SM5_HF16 + 2*256*2)    // 2112
#define SM5_TOT  (SM5_RED + 32*4)        // 2240

__global__ __launch_bounds__(512, 2) void lstm_table(
    const int*   __restrict__ tok,
    const float* __restrict__ Whh,
    const float* __restrict__ Wout,
    const float* __restrict__ bout,
    const _Float16* __restrict__ xgp,
    float*       __restrict__ out)
{
    __shared__ char smem[SM5_TOT];
    const int tid = threadIdx.x;
    const int wv  = tid >> 6;      // 0..7
    const int L   = tid & 63;
    const int l15 = L & 15;
    const int q   = L >> 4;        // row = q&1, jo = q>>1
    const int row = q & 1;
    const int jo  = q >> 1;
    const int g2  = blockIdx.x * 2;
    const int myrow = g2 + row;
    const int jme   = wv*32 + 2*l15 + jo;            // this lane's H column
    const size_t lane_off = (size_t)jme * 4;         // xg entry offset (halfs)

    // ---- W_hh fp8 MX fragments: wf[n][kt], 32 B/lane = k in [kt*128+q*32,+32)
    intx8 wf[8][2];
    #pragma unroll
    for (int n = 0; n < 8; ++n) {
        const int col = (n >> 1)*256 + wv*32 + 2*l15 + (n & 1);
        const float sc = ((n >> 1) == 2) ? TWO_LOG2E : LOG2E;
        #pragma unroll
        for (int kt = 0; kt < 2; ++kt) {
            const float* p = Whh + col*HDIM + kt*128 + q*32;
            intx8 v;
            #pragma unroll
            for (int d = 0; d < 8; ++d) {
                const float4 f = *(const float4*)(p + d*4);
                int pk = __builtin_amdgcn_cvt_pk_fp8_f32(f.x*sc, f.y*sc, 0, false);
                pk     = __builtin_amdgcn_cvt_pk_fp8_f32(f.z*sc, f.w*sc, pk, true);
                v[d] = pk;
            }
            wf[n][kt] = v;
        }
    }

    // ---- prefetch pipeline: 4 xg slots (t%4), tokens depth 8 ----
    union Hx { uint2 v; _Float16 h[4]; };
    uint2 xgS0, xgS1, xgS2, xgS3;
    int   tkS0, tkS1, tkS2, tkS3;
    xgS0 = *(const uint2*)(xgp + (size_t)tok[0*NBATCH + myrow]*1024 + lane_off);
    xgS1 = *(const uint2*)(xgp + (size_t)tok[1*NBATCH + myrow]*1024 + lane_off);
    xgS2 = *(const uint2*)(xgp + (size_t)tok[2*NBATCH + myrow]*1024 + lane_off);
    xgS3 = *(const uint2*)(xgp + (size_t)tok[3*NBATCH + myrow]*1024 + lane_off);
    tkS0 = tok[4*NBATCH + myrow];
    tkS1 = tok[5*NBATCH + myrow];
    tkS2 = tok[6*NBATCH + myrow];
    tkS3 = tok[7*NBATCH + myrow];

    float c = 0.f;

    auto step = [&](int t, int PAR, uint2& xg_slot, int& tk_slot) {
        floatx4 acc[8];
        #pragma unroll
        for (int n = 0; n < 8; ++n) acc[n] = (floatx4){0.f,0.f,0.f,0.f};

        if (t > 0) {
            const char* hb = smem + SM5_H8 + (1-PAR)*H8B5 + (l15 & 1)*HS5 + q*32;
            union { int4 v[2]; intx8 a; } af0, af1;
            af0.v[0] = *(const int4*)(hb);
            af0.v[1] = *(const int4*)(hb + 16);
            af1.v[0] = *(const int4*)(hb + 128);
            af1.v[1] = *(const int4*)(hb + 144);
            #pragma unroll
            for (int n = 0; n < 8; ++n)
                acc[n] = __builtin_amdgcn_mfma_scale_f32_16x16x128_f8f6f4(
                             af0.a, wf[n][0], acc[n], 0, 0, 0, 127, 0, 127);
            #pragma unroll
            for (int n = 0; n < 8; ++n)
                acc[n] = __builtin_amdgcn_mfma_scale_f32_16x16x128_f8f6f4(
                             af1.a, wf[n][1], acc[n], 0, 0, 0, 127, 0, 127);
        }

        // extract this lane's cell: gate g at acc[2g+jo][row]
        float P[4];
        #pragma unroll
        for (int g = 0; g < 4; ++g) {
            const float e0 = row ? acc[2*g  ][1] : acc[2*g  ][0];
            const float e1 = row ? acc[2*g+1][1] : acc[2*g+1][0];
            P[g] = jo ? e1 : e0;
        }
        // consume xg (loaded 4 steps ago — never a dependency wait)
        {
            Hx xv; xv.v = xg_slot;
            P[0] += (float)xv.h[0]; P[1] += (float)xv.h[1];
            P[2] += (float)xv.h[2]; P[3] += (float)xv.h[3];
        }
        // refill the slot for t+4 NOW (before the gate chain) so the load is
        // ~full-step in flight when the barrier's vmcnt(0) drain hits.
        if (t + 4 < T_STEPS)
            xg_slot = *(const uint2*)(xgp + (size_t)tk_slot*1024 + lane_off);
        if (t + 8 < T_STEPS)
            tk_slot = tok[(t+8)*NBATCH + myrow];

        const float iv = sigE(P[0]), fv = sigE(P[1]);
        const float gv = tanhE(P[2]), ov = sigE(P[3]);
        c = fv * c + iv * gv;
        const float hv = ov * tanhE(c * TWO_LOG2E);

        if (t == T_STEPS-1) {
            *(_Float16*)(smem + SM5_HF16 + (row*256 + jme)*2) = (_Float16)hv;
        } else {
            const int pk = __builtin_amdgcn_cvt_pk_fp8_f32(hv, hv, 0, false);
            *(char*)(smem + SM5_H8 + PAR*H8B5 + row*HS5 + jme) = (char)(pk & 0xFF);
        }
        __syncthreads();
    };

    #pragma unroll 1
    for (int t = 0; t < T_STEPS; t += 4) {
        step(t,     0, xgS0, tkS0);
        step(t + 1, 1, xgS1, tkS1);
        step(t + 2, 0, xgS2, tkS2);
        step(t + 3, 1, xgS3, tkS3);
    }

    // ---- output: y = sigmoid(h_T . W_out + b) for 2 rows ----
    float* red = (float*)(smem + SM5_RED);
    if (tid < 32) {
        const int b = tid >> 4, seg = tid & 15;
        const _Float16* hr = (const _Float16*)(smem + SM5_HF16) + b*256 + seg*16;
        const float* wo = Wout + seg*16;
        float s = 0.f;
        #pragma unroll
        for (int jj = 0; jj < 16; ++jj) s += (float)hr[jj] * wo[jj];
        red[tid] = s;
    }
    __syncthreads();
    if (tid < 2) {
        float s = 0.f;
        #pragma unroll
        for (int k = 0; k < 16; ++k) s += red[tid*16 + k];
        out[g2 + tid] = sigm(s + bout[0]);
    }
}

// ============================================================================
// PATH A (fallback, ws < 102.4 MB): Round-1 kernel (proven, ~8.4 ms)
// ============================================================================
#define FLAGS_OFF   0
#define HBUF_OFF    4096
#define EMB16_OFF   (4096 + 262144)
#define EMB16_BYTES (NVOCAB*EDIM*2)
#define WS_NEED_BIG (EMB16_OFF + EMB16_BYTES)

__global__ void emb_cvt_kernel(const float* __restrict__ src, _Float16* __restrict__ dst, int n4){
    int stride = gridDim.x * blockDim.x;
    for (int i = blockIdx.x*blockDim.x + threadIdx.x; i < n4; i += stride) {
        const float4 v = ((const float4*)src)[i];
        union { _Float16 h[4]; uint2 u; } p;
        p.h[0] = (_Float16)v.x; p.h[1] = (_Float16)v.y;
        p.h[2] = (_Float16)v.z; p.h[3] = (_Float16)v.w;
        ((uint2*)dst)[i] = p.u;
    }
}

__global__ __launch_bounds__(64, 2) void lstm_persist(
    const int*   __restrict__ tok,
    const float* __restrict__ emb32,
    const float* __restrict__ Wih,
    const float* __restrict__ Whh,
    const float* __restrict__ bih,
    const float* __restrict__ bhh,
    const float* __restrict__ Wout,
    const float* __restrict__ bout,
    float*       __restrict__ out,
    char*        __restrict__ ws,
    const _Float16* __restrict__ emb16,
    int use16)
{
    const int L      = threadIdx.x;
    const int lane15 = L & 15;
    const int quad   = L >> 4;
    const int bid    = blockIdx.x;
    const int grp    = (bid & 7)*2 + (bid >> 8);
    const int slc    = (bid >> 3) & 31;

    int*      flags = (int*)(ws + FLAGS_OFF);
    _Float16* hbuf  = (_Float16*)(ws + HBUF_OFF);

    half8 bfr[2][12];
    float bias[2];
    #pragma unroll
    for (int tile = 0; tile < 2; ++tile) {
        const int nloc = tile*16 + lane15;
        const int gate = nloc >> 3;
        const int jj   = nloc & 7;
        const int ng   = gate*HDIM + slc*8 + jj;
        bias[tile] = bih[ng] + bhh[ng];
        #pragma unroll
        for (int kt = 0; kt < 12; ++kt) {
            const int k0 = kt*32 + quad*8;
            const float* p = (kt < 4) ? (Wih + ng*EDIM + k0)
                                      : (Whh + ng*HDIM + (k0 - EDIM));
            half8 h;
            #pragma unroll
            for (int i = 0; i < 8; ++i) h[i] = (_Float16)p[i];
            bfr[tile][kt] = h;
        }
    }

    const int btok = grp*16 + lane15;
    auto ldx = [&](int tk, int kt) -> half8 {
        const int k0 = kt*32 + quad*8;
        if (use16) {
            return *(const half8*)(emb16 + (long)tk*EDIM + k0);
        } else {
            const float* p = emb32 + (long)tk*EDIM + k0;
            half8 h;
            #pragma unroll
            for (int i = 0; i < 8; ++i) h[i] = (_Float16)p[i];
            return h;
        }
    };

    int tok_next = tok[NBATCH + btok];
    half8 xcur[4], xnext[4];
    {
        int tok0 = tok[btok];
        #pragma unroll
        for (int kt = 0; kt < 4; ++kt) xcur[kt] = ldx(tok0, kt);
    }

    float c[4] = {0.f, 0.f, 0.f, 0.f};
    const bool act = (lane15 < 8);
    const bool stl = act && !(lane15 & 1);
    const int  jj8 = lane15 & 7;

    #pragma unroll 1
    for (int t = 0; t < T_STEPS; ++t) {
        if (t + 1 < T_STEPS) {
            #pragma unroll
            for (int kt = 0; kt < 4; ++kt) xnext[kt] = ldx(tok_next, kt);
        }
        int tok_nn = 0;
        if (t + 2 < T_STEPS) tok_nn = tok[(t+2)*NBATCH + btok];

        floatx4 acc0 = {0.f,0.f,0.f,0.f};
        floatx4 acc1 = {0.f,0.f,0.f,0.f};

        #pragma unroll
        for (int kt = 0; kt < 4; ++kt) {
            acc0 = __builtin_amdgcn_mfma_f32_16x16x32_f16(xcur[kt], bfr[0][kt], acc0, 0,0,0);
            acc1 = __builtin_amdgcn_mfma_f32_16x16x32_f16(xcur[kt], bfr[1][kt], acc1, 0,0,0);
        }

        if (t > 0) {
            const int parR = (t-1) & 1;
            int* fl = flags + parR*(NGROUPS*NSLICES) + grp*NSLICES + (L & 31);
            int cnt = 0;
            while (true) {
                int v = __hip_atomic_load(fl, __ATOMIC_RELAXED, __HIP_MEMORY_SCOPE_AGENT);
                if (__all(v >= t)) break;
                if (++cnt > (1<<15)) break;
                __builtin_amdgcn_s_sleep(1);
            }
            asm volatile("" ::: "memory");
            const _Float16* hr = hbuf + (parR*NGROUPS + grp)*(16*HDIM) + lane15*HDIM;
            #pragma unroll
            for (int kt = 4; kt < 12; ++kt) {
                const int j0 = (kt-4)*32 + quad*8;
                const uint32* hp = (const uint32*)(hr + j0);
                union { uint32 u[4]; half8 h; } hf;
                hf.u[0] = __hip_atomic_load(hp+0, __ATOMIC_RELAXED, __HIP_MEMORY_SCOPE_AGENT);
                hf.u[1] = __hip_atomic_load(hp+1, __ATOMIC_RELAXED, __HIP_MEMORY_SCOPE_AGENT);
                hf.u[2] = __hip_atomic_load(hp+2, __ATOMIC_RELAXED, __HIP_MEMORY_SCOPE_AGENT);
                hf.u[3] = __hip_atomic_load(hp+3, __ATOMIC_RELAXED, __HIP_MEMORY_SCOPE_AGENT);
                acc0 = __builtin_amdgcn_mfma_f32_16x16x32_f16(hf.h, bfr[0][kt], acc0, 0,0,0);
                acc1 = __builtin_amdgcn_mfma_f32_16x16x32_f16(hf.h, bfr[1][kt], acc1, 0,0,0);
            }
        }

        uint32 hdw[4];
        #pragma unroll
        for (int r = 0; r < 4; ++r) {
            float p0 = acc0[r] + bias[0];
            float p1 = acc1[r] + bias[1];
            float fpre = __int_as_float(__builtin_amdgcn_ds_swizzle(__float_as_int(p0), 0x201F));
            float opre = __int_as_float(__builtin_amdgcn_ds_swizzle(__float_as_int(p1), 0x201F));
            float iv = sigm(p0);
            float fv = sigm(fpre);
            float gv = tanh_fast(p1);
            float ov = sigm(opre);
            float cn = fv * c[r] + iv * gv;
            c[r] = cn;
            float hv = ov * tanh_fast(cn);
            union { _Float16 f; unsigned short u; } cvh; cvh.f = (_Float16)hv;
            uint32 hu = cvh.u;
            uint32 part = (uint32)__builtin_amdgcn_ds_swizzle((int)hu, 0x041F);
            hdw[r] = (hu & 0xFFFFu) | (part << 16);
        }
        {
            _Float16* hwb = hbuf + (((t&1)*NGROUPS) + grp)*(16*HDIM);
            if (stl) {
                #pragma unroll
                for (int r = 0; r < 4; ++r) {
                    const int m = quad*4 + r;
                    uint32* dst = (uint32*)(hwb + m*HDIM + slc*8 + jj8);
                    __hip_atomic_store(dst, hdw[r], __ATOMIC_RELAXED, __HIP_MEMORY_SCOPE_AGENT);
                }
            }
            asm volatile("s_waitcnt vmcnt(0)" ::: "memory");
            if (L == 0) {
                int* myf = flags + (t&1)*(NGROUPS*NSLICES) + grp*NSLICES + slc;
                __hip_atomic_store(myf, t+1, __ATOMIC_RELAXED, __HIP_MEMORY_SCOPE_AGENT);
            }
        }
        #pragma unroll
        for (int kt = 0; kt < 4; ++kt) xcur[kt] = xnext[kt];
        tok_next = tok_nn;
    }

    if (slc == 0) {
        const int parF = (T_STEPS-1) & 1;
        int* fl = flags + parF*(NGROUPS*NSLICES) + grp*NSLICES + (L & 31);
        int cnt = 0;
        while (true) {
            int v = __hip_atomic_load(fl, __ATOMIC_RELAXED, __HIP_MEMORY_SCOPE_AGENT);
            if (__all(v >= T_STEPS)) break;
            if (++cnt > (1<<15)) break;
            __builtin_amdgcn_s_sleep(1);
        }
        asm volatile("" ::: "memory");
        const int m  = L >> 2;
        const int pp = L & 3;
        const _Float16* hr = hbuf + (parF*NGROUPS + grp)*(16*HDIM) + m*HDIM;
        const uint32* hp = (const uint32*)hr + pp*32;
        float sum = 0.f;
        #pragma unroll
        for (int d = 0; d < 32; ++d) {
            uint32 u = __hip_atomic_load(hp + d, __ATOMIC_RELAXED, __HIP_MEMORY_SCOPE_AGENT);
            union { uint32 u; _Float16 h[2]; } cv; cv.u = u;
            const int j = pp*64 + d*2;
            sum += (float)cv.h[0] * Wout[j] + (float)cv.h[1] * Wout[j+1];
        }
        sum += __int_as_float(__builtin_amdgcn_ds_swizzle(__float_as_int(sum), 0x041F));
        sum += __int_as_float(__builtin_amdgcn_ds_swizzle(__float_as_int(sum), 0x081F));
        if (pp == 0) out[grp*16 + m] = sigm(sum + bout[0]);
    }
}

// ============================================================================
extern "C" void kernel_launch(void* const* d_in, const int* in_sizes, int n_in,
                              void* d_out, int out_size, void* d_ws, size_t ws_size,
                              hipStream_t stream) {
    const int*   tokp = (const int*)  d_in[0];
    const float* emb  = (const float*)d_in[1];
    const float* Wih  = (const float*)d_in[2];
    const float* Whh  = (const float*)d_in[3];
    const float* bih  = (const float*)d_in[4];
    const float* bhh  = (const float*)d_in[5];
    const float* Wout = (const float*)d_in[6];
    const float* bout = (const float*)d_in[7];
    float* out = (float*)d_out;
    char*  ws  = (char*)d_ws;

    if (ws_size >= TABLE_BYTES) {
        _Float16* xgp = (_Float16*)ws;
        const int vtiles = (NVOCAB + 63) / 64;          // 782
        xg_table<<<vtiles*8, 64, 0, stream>>>(emb, Wih, bih, bhh, xgp);
        lstm_table<<<NBLK5, 512, 0, stream>>>(tokp, Whh, Wout, bout, xgp, out);
    } else {
        const int use16 = (ws_size >= (size_t)WS_NEED_BIG) ? 1 : 0;
        _Float16* emb16 = (_Float16*)(ws + EMB16_OFF);
        if (use16) {
            emb_cvt_kernel<<<1024, 256, 0, stream>>>(emb, emb16, NVOCAB*EDIM/4);
        }
        lstm_persist<<<NBLOCKS, 64, 0, stream>>>(tokp, emb, Wih, Whh, bih, bhh, Wout, bout,
                                                 out, ws, emb16, use16);
    }
}